// Round 5
// baseline (264.986 us; speedup 1.0000x reference)
//
#include <hip/hip_runtime.h>

// ---------------------------------------------------------------------------
// PointTransformerForSegmentation, round 10:
//   convert   : bf16-cast w0feat / w0pos / w1 / feat2
//   fgemm     : F[b*128+n2][512] = feat2 . W0feat^T   (f32, tiny GEMM)
//   build_h0  : kNN + pos embed + K=32 MFMA + F gather -> H0 plane-major bf16
//               grid 256x4: blockIdx.y owns a 128-wide H0 column slice.
//   gemm2     : BM=128 x BN=256, BK=32, 512 thr (8 waves 2Mx4N, 64x64/wave).
//               6-deep LDS pipeline (144 KiB), per step: B1 -> stage(kt+5)
//               -> vmcnt(15) -> B2 -> 8 ds_read + 16 MFMA with NO lgkmcnt
//               drain (compiler-counted waits interleave reads with MFMAs;
//               waves drift between barriers -> LDS || MFMA overlap).
//               Swapped-operand MFMA: C cols = queries -> coalesced out.
// LDS layout: fragment-linear 1KB groups (16 rows x 32 k), lane l at
// group*1024 + l*16 -> sequential banks, zero conflicts.
// ---------------------------------------------------------------------------

typedef unsigned short u16;
typedef __bf16 bf16x8 __attribute__((ext_vector_type(8)));
typedef float f32x4 __attribute__((ext_vector_type(4)));
typedef u16 u16x4 __attribute__((ext_vector_type(4)));

#define BQ 8
#define N1Q 2048
#define N2Q 128
#define C2Q 256
#define DPOS 32
#define H0Q 512
#define H1Q 1024
#define NQ (BQ * N1Q)   // 16384 queries

// workspace layout (bytes)
#define WS_W0F 0u          // 512*256*2   = 262144
#define WS_W0P 262144u     // 512*32*2    = 32768
#define WS_W1 294912u      // 1024*512*2  = 1048576
#define WS_F2B 1343488u    // 1024*256*2  = 524288
#define WS_F 1867776u      // 1024*512*4  = 2097152
#define WS_H0 3964928u     // 3*16384*512*2 = 50331648 (end 54296576)

__device__ __forceinline__ u16 f2bf(float f) {
  unsigned int u = __builtin_bit_cast(unsigned int, f);
  return (u16)((u + 0x7FFFu + ((u >> 16) & 1u)) >> 16);
}

__device__ __forceinline__ void load16_lds(const void* g, void* l) {
  __builtin_amdgcn_global_load_lds(
      (const __attribute__((address_space(1))) unsigned int*)g,
      (__attribute__((address_space(3))) unsigned int*)l, 16, 0, 0);
}

// ---------------------------------------------------------------------------
// convert: w0feat (512x256), w0pos (512x32), w1 (1024x512), feat2 (1024x256)
__global__ void convert_inputs(const float* __restrict__ w0,
                               const float* __restrict__ w1,
                               const float* __restrict__ feat2,
                               u16* __restrict__ w0f, u16* __restrict__ w0p,
                               u16* __restrict__ w1b, u16* __restrict__ f2b) {
  int i = blockIdx.x * 256 + threadIdx.x;  // grid covers 933888 exactly
  if (i < 131072) {
    int h = i >> 8, c = i & 255;
    w0f[i] = f2bf(w0[h * 288 + c]);
  } else if (i < 147456) {
    int j = i - 131072;
    int h = j >> 5, c = j & 31;
    w0p[j] = f2bf(w0[h * 288 + 256 + c]);
  } else if (i < 671744) {
    int j = i - 147456;
    w1b[j] = f2bf(w1[j]);
  } else {
    int j = i - 671744;  // < 262144
    f2b[j] = f2bf(feat2[j]);
  }
}

// ---------------------------------------------------------------------------
// fgemm: F[m][n] = sum_k feat2bf[m][k]*w0featbf[n][k], f32 out.
// M=1024 N=512 K=256, 128x128 tile, 32 blocks.
__global__ __launch_bounds__(256, 2) void fgemm(const u16* __restrict__ A,
                                                const u16* __restrict__ W,
                                                float* __restrict__ F) {
  __shared__ alignas(16) u16 As[128 * 32];
  __shared__ alignas(16) u16 Bs[128 * 32];
  const int m0 = (blockIdx.x >> 2) * 128, n0 = (blockIdx.x & 3) * 128;
  const int t = threadIdx.x;
  const int wv = t >> 6, lane = t & 63;
  const int wm = wv >> 1, wn = wv & 1;
  const int quad = lane >> 4, cc = lane & 15;
  const int srow = lane & 15, skc = quad * 8;
  f32x4 acc[4][4] = {};

  for (int k0 = 0; k0 < 256; k0 += 32) {
#pragma unroll
    for (int i = 0; i < 2; i++) {
      int g = i * 4 + wv;
      load16_lds(A + (size_t)(m0 + g * 16 + srow) * 256 + k0 + skc,
                 (char*)As + g * 1024 + (lane << 4));
      load16_lds(W + (size_t)(n0 + g * 16 + srow) * 256 + k0 + skc,
                 (char*)Bs + g * 1024 + (lane << 4));
    }
    __syncthreads();
    bf16x8 af[4], bf[4];
#pragma unroll
    for (int mt = 0; mt < 4; mt++)
      af[mt] = *(const bf16x8*)((const char*)As + (wm * 4 + mt) * 1024 + (lane << 4));
#pragma unroll
    for (int nt = 0; nt < 4; nt++)
      bf[nt] = *(const bf16x8*)((const char*)Bs + (wn * 4 + nt) * 1024 + (lane << 4));
#pragma unroll
    for (int mt = 0; mt < 4; mt++)
#pragma unroll
      for (int nt = 0; nt < 4; nt++)
        acc[mt][nt] = __builtin_amdgcn_mfma_f32_16x16x32_bf16(
            af[mt], bf[nt], acc[mt][nt], 0, 0, 0);
    __syncthreads();
  }

#pragma unroll
  for (int nt = 0; nt < 4; nt++) {
    int gn = n0 + wn * 64 + nt * 16 + cc;
#pragma unroll
    for (int mt = 0; mt < 4; mt++) {
      int gm = m0 + wm * 64 + mt * 16 + quad * 4;
#pragma unroll
      for (int r = 0; r < 4; r++)
        F[(size_t)(gm + r) * H0Q + gn] = acc[mt][nt][r];
    }
  }
}

// ---------------------------------------------------------------------------
// build_h0: block = (64 queries) x (128-wide H0 column slice via blockIdx.y).
// Phase 1a: 4-way-parallel kNN scan. Phase 1b: t<64 merge (serial tie order).
// Phase 1c: t<192 pos embed. Phase 2: one 128-col slice of
// H0 = relu((F[idx] + pos.W0pos^T)*s0 + b0), plane-major, no pad rows.
__global__ __launch_bounds__(256, 2) void build_h0(
    const float* __restrict__ xyz1, const float* __restrict__ xyz2,
    const float* __restrict__ lrf2, const float* __restrict__ w_pos,
    const float* __restrict__ pscale, const float* __restrict__ pbias,
    const u16* __restrict__ w0p, const float* __restrict__ F,
    const float* __restrict__ s0, const float* __restrict__ b0,
    u16* __restrict__ H0) {
  __shared__ float xyz2s[N2Q * 3];
  __shared__ float n2s[N2Q];
  __shared__ float lrfs[N2Q * 9];
  __shared__ float wps[DPOS * 4];
  __shared__ float pss[DPOS];
  __shared__ float pbs[DPOS];
  __shared__ int idxb[192];
  __shared__ float candd[64 * 13];  // stride 13: conflict-free merge reads
  __shared__ int candi[64 * 13];
  __shared__ alignas(16) u16 posb[12 * 512];  // 12 groups x (16 rows x 32)

  const int t = threadIdx.x;
  const int qb = blockIdx.x * 64;
  const int b = qb >> 11;
  const int n0 = blockIdx.y << 7;  // 128-wide column slice

  for (int i = t; i < N2Q * 3; i += 256) xyz2s[i] = xyz2[b * N2Q * 3 + i];
  for (int i = t; i < N2Q * 9; i += 256) lrfs[i] = lrf2[b * N2Q * 9 + i];
  if (t < DPOS * 4) wps[t] = w_pos[t];
  if (t < DPOS) { pss[t] = pscale[t]; pbs[t] = pbias[t]; }
  __syncthreads();
  if (t < N2Q) {
    float x = xyz2s[t * 3], y = xyz2s[t * 3 + 1], z = xyz2s[t * 3 + 2];
    n2s[t] = x * x + y * y + z * z;
  }
  __syncthreads();

  // ---- phase 1a: partial kNN, 4 threads per query ----
  {
    const int ql = t >> 2, qt = t & 3;
    const int q = qb + ql;
    const float px = xyz1[q * 3], py = xyz1[q * 3 + 1], pz = xyz1[q * 3 + 2];
    const float pn = px * px + py * py + pz * pz;
    float d0 = 1e30f, d1 = 1e30f, d2v = 1e30f;
    int i0 = 0, i1 = 0, i2 = 0;
    const int ibeg = qt * 32;
    for (int i = ibeg; i < ibeg + 32; i++) {
      float dt = px * xyz2s[i * 3] + py * xyz2s[i * 3 + 1] + pz * xyz2s[i * 3 + 2];
      float d = pn + n2s[i] - 2.f * dt;
      if (d < d0) {
        d2v = d1; i2 = i1; d1 = d0; i1 = i0; d0 = d; i0 = i;
      } else if (d < d1) {
        d2v = d1; i2 = i1; d1 = d; i1 = i;
      } else if (d < d2v) {
        d2v = d; i2 = i;
      }
    }
    int base = ql * 13 + qt * 3;
    candd[base] = d0;      candi[base] = i0;
    candd[base + 1] = d1;  candi[base + 1] = i1;
    candd[base + 2] = d2v; candi[base + 2] = i2;
  }
  __syncthreads();

  // ---- phase 1b: merge 12 candidates per query (t<64) ----
  if (t < 64) {
    float d0 = 1e30f, d1 = 1e30f, d2v = 1e30f;
    int i0 = 0, i1 = 0, i2 = 0;
    int base = t * 13;
#pragma unroll
    for (int c = 0; c < 12; c++) {
      float d = candd[base + c];
      int id = candi[base + c];
      if (d < d0) {
        d2v = d1; i2 = i1; d1 = d0; i1 = i0; d0 = d; i0 = id;
      } else if (d < d1) {
        d2v = d1; i2 = i1; d1 = d; i1 = id;
      } else if (d < d2v) {
        d2v = d; i2 = id;
      }
    }
    idxb[t] = i0;
    idxb[64 + t] = i1;
    idxb[128 + t] = i2;
  }
  __syncthreads();

  // ---- phase 1c: pos embed, one (query, neighbor) per thread (t<192) ----
  if (t < 192) {
    const int ql = t & 63;
    const int q = qb + ql;
    const float px = xyz1[q * 3], py = xyz1[q * 3 + 1], pz = xyz1[q * 3 + 2];
    const int id = idxb[t];
    float rx = px - xyz2s[id * 3];
    float ry = py - xyz2s[id * 3 + 1];
    float rz = pz - xyz2s[id * 3 + 2];
    float rn = sqrtf(rx * rx + ry * ry + rz * rz);
    float inv = 1.f / fmaxf(rn, 1e-12f);
    float ux = rx * inv, uy = ry * inv, uz = rz * inv;
    const float* L = lrfs + id * 9;
    float a0 = L[0] * ux + L[1] * uy + L[2] * uz;
    float a1 = L[3] * ux + L[4] * uy + L[5] * uz;
    float a2 = L[6] * ux + L[7] * uy + L[8] * uz;
    u16* pd = posb + (t >> 4) * 512 + (t & 15) * 8;
#pragma unroll
    for (int o = 0; o < DPOS; o++) {
      float v = wps[o * 4] * rn + wps[o * 4 + 1] * a0 + wps[o * 4 + 2] * a1 +
                wps[o * 4 + 3] * a2;
      v = v * pss[o] + pbs[o];
      v = (v >= 0.f) ? v : 0.2f * v;  // LeakyReLU(0.2)
      pd[(o >> 3) * 128 + (o & 7)] = f2bf(v);
    }
  }
  __syncthreads();

  // ---- phase 2: H0[:, n0:n0+128] = relu((F[idx] + pos.W0pos^T)*s0 + b0) ----
  const int wv = t >> 6, lane = t & 63;
  const int quad = lane >> 4, cc = lane & 15;
  const float* Fr[3];
  u16* Hr[3];
#pragma unroll
  for (int mt = 0; mt < 3; mt++) {
    int rl = wv * 48 + mt * 16 + cc;  // wave's rows: groups 3*wv+mt
    Fr[mt] = F + ((size_t)(b * N2Q + idxb[rl])) * H0Q;
    int jj = rl >> 6, ql = rl & 63;
    Hr[mt] = H0 + ((size_t)(jj * NQ) + qb + ql) * H0Q;
  }
  bf16x8 afr[3];
#pragma unroll
  for (int mt = 0; mt < 3; mt++)
    afr[mt] = *(const bf16x8*)((const char*)posb + (wv * 3 + mt) * 1024 + (lane << 4));
  const f32x4 zf = {};
  bf16x8 bfr[8];
#pragma unroll
  for (int nt = 0; nt < 8; nt++)
    bfr[nt] = *(const bf16x8*)(w0p + (n0 + nt * 16 + cc) * 32 + quad * 8);
  f32x4 acc[3][8];
#pragma unroll
  for (int mt = 0; mt < 3; mt++)
#pragma unroll
    for (int nt = 0; nt < 8; nt++)  // swapped operands: C row=h, col=query
      acc[mt][nt] = __builtin_amdgcn_mfma_f32_16x16x32_bf16(bfr[nt], afr[mt],
                                                            zf, 0, 0, 0);
#pragma unroll
  for (int nt = 0; nt < 8; nt++) {
    int hb = n0 + nt * 16 + quad * 4;
    f32x4 sv = *(const f32x4*)(s0 + hb);
    f32x4 bvv = *(const f32x4*)(b0 + hb);
#pragma unroll
    for (int mt = 0; mt < 3; mt++) {
      f32x4 fv = *(const f32x4*)(Fr[mt] + hb);
      u16x4 o4;
#pragma unroll
      for (int r = 0; r < 4; r++) {
        float h = (fv[r] + acc[mt][nt][r]) * sv[r] + bvv[r];
        h = h > 0.f ? h : 0.f;
        o4[r] = f2bf(h);
      }
      *(u16x4*)(Hr[mt] + hb) = o4;
    }
  }
}

// ---------------------------------------------------------------------------
// gemm2: out[b][n][n1] = sum_j relu((H0_j[q][:] . W1[n][:])*s1[n] + b1[n]).
// BM=128 (queries) x BN=256 (H1), BK=32, 48 K-steps (3 planes x 16).
// 512 threads = 8 waves (2M x 4N), per-wave C = 64x64.
// 6-deep pipeline (A 8KB + B 16KB per step = 144 KiB LDS):
//   B1; stage(kt+5 -> buf[(kt+5)%6]) [3 loads/thr]; vmcnt(15); B2;
//   8 ds_read + 16 MFMA -- no lgkmcnt drain, compiler-counted waits.
// Swapped operands: mfma(bf,af) -> C row = gn frag, col = query -> the
// epilogue writes 16-lane-contiguous n1 segments (64B) instead of 4B scatter.
__global__ __launch_bounds__(512, 2) void gemm2(const u16* __restrict__ A,
                                                const u16* __restrict__ W,
                                                const float* __restrict__ s,
                                                const float* __restrict__ bz,
                                                float* __restrict__ out) {
  __shared__ alignas(16) u16 As[6][128 * 32];  // 8 KB per step
  __shared__ alignas(16) u16 Bs[6][256 * 32];  // 16 KB per step
  const int id = blockIdx.x;            // 512 blocks
  const int xcd = id & 7, g = id >> 3;  // g 0..63
  const int m0 = (xcd * 16 + (g >> 2)) * 128;  // 16 m-tiles per XCD
  const int n0 = (g & 3) * 256;
  const int t = threadIdx.x;
  const int wv = t >> 6, lane = t & 63;
  const int wm = wv >> 2, wn = wv & 3;  // 2M x 4N wave grid
  const int quad = lane >> 4, cc = lane & 15;
  const int lr = lane & 15, lk = (lane >> 4) * 8;

  // staging source offsets (elements; + (kt&15)*32 per step, + plane)
  const size_t aBase = (size_t)(m0 + wv * 16 + lr) * 512 + lk;
  const size_t bBase0 = (size_t)(n0 + wv * 32 + lr) * 512 + lk;
  const size_t bBase1 = bBase0 + (size_t)16 * 512;
  const int adst = wv * 1024 + (lane << 4);
  const int bdst0 = (wv * 2) * 1024 + (lane << 4);
  const int bdst1 = (wv * 2 + 1) * 1024 + (lane << 4);

  // per-lane scale/bias: gn = n0 + wn*64 + nt*16 + quad*4 + r
  f32x4 sv4[4], bv4[4];
#pragma unroll
  for (int nt = 0; nt < 4; nt++) {
    int gnb = n0 + wn * 64 + nt * 16 + quad * 4;
    sv4[nt] = *(const f32x4*)(s + gnb);
    bv4[nt] = *(const f32x4*)(bz + gnb);
  }
  // force the s/b loads to complete NOW so the compiler doesn't inject a
  // vmcnt(0) drain at the plane-boundary folds inside the pipelined loop.
#pragma unroll
  for (int nt = 0; nt < 4; nt++)
#pragma unroll
    for (int r = 0; r < 4; r++) {
      float a = sv4[nt][r], c = bv4[nt][r];
      asm volatile("" : "+v"(a), "+v"(c));
      sv4[nt][r] = a; bv4[nt][r] = c;
    }

  auto stage = [&](int kt, int bi) {
    const u16* Ap = A + (size_t)(kt >> 4) * ((size_t)NQ * H0Q) + ((kt & 15) << 5);
    const u16* Wp = W + ((kt & 15) << 5);
    load16_lds(Ap + aBase, (char*)As[bi] + adst);
    load16_lds(Wp + bBase0, (char*)Bs[bi] + bdst0);
    load16_lds(Wp + bBase1, (char*)Bs[bi] + bdst1);
  };

  f32x4 sum[4][4] = {};
  f32x4 acc[4][4] = {};

  auto compute = [&](int bi) {
    bf16x8 af[4], bf[4];
    const char* ab = (const char*)As[bi] + (lane << 4);
    const char* bb = (const char*)Bs[bi] + (lane << 4);
#pragma unroll
    for (int mt = 0; mt < 4; mt++)
      af[mt] = *(const bf16x8*)(ab + (wm * 4 + mt) * 1024);
#pragma unroll
    for (int nt = 0; nt < 4; nt++)
      bf[nt] = *(const bf16x8*)(bb + (wn * 4 + nt) * 1024);
    __builtin_amdgcn_s_setprio(1);
#pragma unroll
    for (int mt = 0; mt < 4; mt++)
#pragma unroll
      for (int nt = 0; nt < 4; nt++)  // swapped: C row=gn frag, col=query
        acc[mt][nt] = __builtin_amdgcn_mfma_f32_16x16x32_bf16(
            bf[nt], af[mt], acc[mt][nt], 0, 0, 0);
    __builtin_amdgcn_s_setprio(0);
  };

  auto fold = [&]() {
#pragma unroll
    for (int mt = 0; mt < 4; mt++)
#pragma unroll
      for (int nt = 0; nt < 4; nt++) {
#pragma unroll
        for (int r = 0; r < 4; r++) {
          float h = acc[mt][nt][r] * sv4[nt][r] + bv4[nt][r];
          sum[mt][nt][r] += (h > 0.f ? h : 0.f);
        }
        acc[mt][nt] = f32x4{};
      }
  };

#pragma unroll
  for (int kt = 0; kt < 5; kt++) stage(kt, kt);

  int bi = 0;
  for (int kt = 0; kt < 43; kt++) {
    __builtin_amdgcn_s_barrier();                       // B1: buf[kt-1] free
    stage(kt + 5, bi == 0 ? 5 : bi - 1);                // -> buf[(kt+5)%6]
    asm volatile("s_waitcnt vmcnt(15)" ::: "memory");   // step kt landed
    __builtin_amdgcn_s_barrier();                       // B2: all waves'
    compute(bi);
    if ((kt & 15) == 15) fold();                        // kt 15, 31
    bi = (bi == 5) ? 0 : bi + 1;
  }
#define TAILSTEP(VM)                                     \
  __builtin_amdgcn_s_barrier();                          \
  asm volatile("s_waitcnt vmcnt(" #VM ")" ::: "memory"); \
  __builtin_amdgcn_s_barrier();                          \
  compute(bi);                                           \
  bi = (bi == 5) ? 0 : bi + 1;
  TAILSTEP(12)   // kt 43
  TAILSTEP(9)    // kt 44
  TAILSTEP(6)    // kt 45
  TAILSTEP(3)    // kt 46
  TAILSTEP(0)    // kt 47
#undef TAILSTEP
  fold();

  // epilogue: lanes write contiguous n1 (query) runs of 64B per (gn row)
#pragma unroll
  for (int nt = 0; nt < 4; nt++) {
#pragma unroll
    for (int mt = 0; mt < 4; mt++) {
      int q = m0 + wm * 64 + mt * 16 + cc;
      int bb2 = q >> 11, n1 = q & 2047;
#pragma unroll
      for (int r = 0; r < 4; r++) {
        int gn = n0 + wn * 64 + nt * 16 + quad * 4 + r;
        out[((size_t)bb2 * H1Q + gn) * N1Q + n1] = sum[mt][nt][r];
      }
    }
  }
}

// ---------------------------------------------------------------------------
extern "C" void kernel_launch(void* const* d_in, const int* in_sizes, int n_in,
                              void* d_out, int out_size, void* d_ws,
                              size_t ws_size, hipStream_t stream) {
  const float* xyz1 = (const float*)d_in[0];
  const float* xyz2 = (const float*)d_in[1];
  const float* feat2 = (const float*)d_in[2];
  const float* lrf2 = (const float*)d_in[3];
  const float* w_pos = (const float*)d_in[4];
  const float* pscale = (const float*)d_in[5];
  const float* pbias = (const float*)d_in[6];
  const float* w0 = (const float*)d_in[7];
  const float* s0 = (const float*)d_in[8];
  const float* b0 = (const float*)d_in[9];
  const float* w1 = (const float*)d_in[10];
  const float* s1 = (const float*)d_in[11];
  const float* b1 = (const float*)d_in[12];
  float* out = (float*)d_out;

  char* ws = (char*)d_ws;
  u16* w0f = (u16*)(ws + WS_W0F);
  u16* w0p = (u16*)(ws + WS_W0P);
  u16* w1b = (u16*)(ws + WS_W1);
  u16* f2b = (u16*)(ws + WS_F2B);
  float* F = (float*)(ws + WS_F);
  u16* H0 = (u16*)(ws + WS_H0);

  convert_inputs<<<933888 / 256, 256, 0, stream>>>(w0, w1, feat2, w0f, w0p,
                                                   w1b, f2b);
  fgemm<<<32, 256, 0, stream>>>(f2b, w0f, F);
  build_h0<<<dim3(NQ / 64, 4), 256, 0, stream>>>(xyz1, xyz2, lrf2, w_pos,
                                                 pscale, pbias, w0p, F, s0,
                                                 b0, H0);
  gemm2<<<512, 512, 0, stream>>>(H0, w1b, s1, b1, out);
}

// Round 6
// 256.795 us; speedup vs baseline: 1.0319x; 1.0319x over previous
//
#include <hip/hip_runtime.h>

// ---------------------------------------------------------------------------
// PointTransformerForSegmentation, round 11:
//   convert   : bf16-cast w0feat / w0pos / w1 / feat2
//   fgemm     : F[b*128+n2][512] = feat2 . W0feat^T   (f32, tiny GEMM)
//   build_h0  : kNN + pos embed + K=32 MFMA + F gather -> H0 plane-major bf16
//               NEW: per-slice LDS transpose staging -> fully coalesced
//               16B-chunk H0 row writes (was 96 scattered 8B stores/thread).
//   gemm2     : NEW geometry BM=64 queries x BN=512, K = 3 planes x 512.
//               A (H0, 50MB) streamed ~once; W1 (1MB) is the re-read operand
//               and stays L2-resident per XCD (q-tile pairs packed per XCD).
//               Double-buffered 72KB K-tiles (BK=64), counted vmcnt(9),
//               in-place stage after lgkm-drain barrier (R4-proven skeleton),
//               32 MFMA/wave/tile, relu-fold at plane boundaries.
//               Epilogue: LDS transpose -> coalesced f32x4 row stores
//               (was 64 scattered 4B stores/thread).
// LDS layout: fragment-linear 1KB groups (16 rows x 32 k), lane l at
// group*1024 + l*16 -> sequential banks, zero conflicts.
// ---------------------------------------------------------------------------

typedef unsigned short u16;
typedef __bf16 bf16x8 __attribute__((ext_vector_type(8)));
typedef float f32x4 __attribute__((ext_vector_type(4)));
typedef u16 u16x4 __attribute__((ext_vector_type(4)));
typedef u16 u16x8 __attribute__((ext_vector_type(8)));

#define BQ 8
#define N1Q 2048
#define N2Q 128
#define C2Q 256
#define DPOS 32
#define H0Q 512
#define H1Q 1024
#define NQ (BQ * N1Q)   // 16384 queries

// workspace layout (bytes)
#define WS_W0F 0u          // 512*256*2   = 262144
#define WS_W0P 262144u     // 512*32*2    = 32768
#define WS_W1 294912u      // 1024*512*2  = 1048576
#define WS_F2B 1343488u    // 1024*256*2  = 524288
#define WS_F 1867776u      // 1024*512*4  = 2097152
#define WS_H0 3964928u     // 3*16384*512*2 = 50331648 (end 54296576)

__device__ __forceinline__ u16 f2bf(float f) {
  unsigned int u = __builtin_bit_cast(unsigned int, f);
  return (u16)((u + 0x7FFFu + ((u >> 16) & 1u)) >> 16);
}

__device__ __forceinline__ void load16_lds(const void* g, void* l) {
  __builtin_amdgcn_global_load_lds(
      (const __attribute__((address_space(1))) unsigned int*)g,
      (__attribute__((address_space(3))) unsigned int*)l, 16, 0, 0);
}

// ---------------------------------------------------------------------------
// convert: w0feat (512x256), w0pos (512x32), w1 (1024x512), feat2 (1024x256)
__global__ void convert_inputs(const float* __restrict__ w0,
                               const float* __restrict__ w1,
                               const float* __restrict__ feat2,
                               u16* __restrict__ w0f, u16* __restrict__ w0p,
                               u16* __restrict__ w1b, u16* __restrict__ f2b) {
  int i = blockIdx.x * 256 + threadIdx.x;  // grid covers 933888 exactly
  if (i < 131072) {
    int h = i >> 8, c = i & 255;
    w0f[i] = f2bf(w0[h * 288 + c]);
  } else if (i < 147456) {
    int j = i - 131072;
    int h = j >> 5, c = j & 31;
    w0p[j] = f2bf(w0[h * 288 + 256 + c]);
  } else if (i < 671744) {
    int j = i - 147456;
    w1b[j] = f2bf(w1[j]);
  } else {
    int j = i - 671744;  // < 262144
    f2b[j] = f2bf(feat2[j]);
  }
}

// ---------------------------------------------------------------------------
// fgemm: F[m][n] = sum_k feat2bf[m][k]*w0featbf[n][k], f32 out.
// M=1024 N=512 K=256, 128x128 tile, 32 blocks.
__global__ __launch_bounds__(256, 2) void fgemm(const u16* __restrict__ A,
                                                const u16* __restrict__ W,
                                                float* __restrict__ F) {
  __shared__ alignas(16) u16 As[128 * 32];
  __shared__ alignas(16) u16 Bs[128 * 32];
  const int m0 = (blockIdx.x >> 2) * 128, n0 = (blockIdx.x & 3) * 128;
  const int t = threadIdx.x;
  const int wv = t >> 6, lane = t & 63;
  const int wm = wv >> 1, wn = wv & 1;
  const int quad = lane >> 4, cc = lane & 15;
  const int srow = lane & 15, skc = quad * 8;
  f32x4 acc[4][4] = {};

  for (int k0 = 0; k0 < 256; k0 += 32) {
#pragma unroll
    for (int i = 0; i < 2; i++) {
      int g = i * 4 + wv;
      load16_lds(A + (size_t)(m0 + g * 16 + srow) * 256 + k0 + skc,
                 (char*)As + g * 1024 + (lane << 4));
      load16_lds(W + (size_t)(n0 + g * 16 + srow) * 256 + k0 + skc,
                 (char*)Bs + g * 1024 + (lane << 4));
    }
    __syncthreads();
    bf16x8 af[4], bf[4];
#pragma unroll
    for (int mt = 0; mt < 4; mt++)
      af[mt] = *(const bf16x8*)((const char*)As + (wm * 4 + mt) * 1024 + (lane << 4));
#pragma unroll
    for (int nt = 0; nt < 4; nt++)
      bf[nt] = *(const bf16x8*)((const char*)Bs + (wn * 4 + nt) * 1024 + (lane << 4));
#pragma unroll
    for (int mt = 0; mt < 4; mt++)
#pragma unroll
      for (int nt = 0; nt < 4; nt++)
        acc[mt][nt] = __builtin_amdgcn_mfma_f32_16x16x32_bf16(
            af[mt], bf[nt], acc[mt][nt], 0, 0, 0);
    __syncthreads();
  }

#pragma unroll
  for (int nt = 0; nt < 4; nt++) {
    int gn = n0 + wn * 64 + nt * 16 + cc;
#pragma unroll
    for (int mt = 0; mt < 4; mt++) {
      int gm = m0 + wm * 64 + mt * 16 + quad * 4;
#pragma unroll
      for (int r = 0; r < 4; r++)
        F[(size_t)(gm + r) * H0Q + gn] = acc[mt][nt][r];
    }
  }
}

// ---------------------------------------------------------------------------
// build_h0: block = 64 queries (256 blocks).
// Phase 1a: 4-way-parallel kNN scan. Phase 1b: t<64 merge (serial tie order).
// Phase 1c: t<192 pos embed. Phase 2: per 128-col slice, MFMA + F-gather +
// scale/bias/relu into LDS hstage, then COALESCED 16B-chunk H0 row writes.
__global__ __launch_bounds__(256, 2) void build_h0(
    const float* __restrict__ xyz1, const float* __restrict__ xyz2,
    const float* __restrict__ lrf2, const float* __restrict__ w_pos,
    const float* __restrict__ pscale, const float* __restrict__ pbias,
    const u16* __restrict__ w0p, const float* __restrict__ F,
    const float* __restrict__ s0, const float* __restrict__ b0,
    u16* __restrict__ H0) {
  __shared__ float xyz2s[N2Q * 3];
  __shared__ float n2s[N2Q];
  __shared__ float lrfs[N2Q * 9];
  __shared__ float wps[DPOS * 4];
  __shared__ float pss[DPOS];
  __shared__ float pbs[DPOS];
  __shared__ int idxb[192];
  __shared__ float candd[64 * 13];  // stride 13: conflict-free merge reads
  __shared__ int candi[64 * 13];
  __shared__ alignas(16) u16 posb[12 * 512];     // 12 groups x (16 rows x 32)
  __shared__ alignas(16) u16 hstage[192 * 136];  // slice out, stride 136 u16

  const int t = threadIdx.x;
  const int qb = blockIdx.x * 64;
  const int b = qb >> 11;

  for (int i = t; i < N2Q * 3; i += 256) xyz2s[i] = xyz2[b * N2Q * 3 + i];
  for (int i = t; i < N2Q * 9; i += 256) lrfs[i] = lrf2[b * N2Q * 9 + i];
  if (t < DPOS * 4) wps[t] = w_pos[t];
  if (t < DPOS) { pss[t] = pscale[t]; pbs[t] = pbias[t]; }
  __syncthreads();
  if (t < N2Q) {
    float x = xyz2s[t * 3], y = xyz2s[t * 3 + 1], z = xyz2s[t * 3 + 2];
    n2s[t] = x * x + y * y + z * z;
  }
  __syncthreads();

  // ---- phase 1a: partial kNN, 4 threads per query ----
  {
    const int ql = t >> 2, qt = t & 3;
    const int q = qb + ql;
    const float px = xyz1[q * 3], py = xyz1[q * 3 + 1], pz = xyz1[q * 3 + 2];
    const float pn = px * px + py * py + pz * pz;
    float d0 = 1e30f, d1 = 1e30f, d2v = 1e30f;
    int i0 = 0, i1 = 0, i2 = 0;
    const int ibeg = qt * 32;
    for (int i = ibeg; i < ibeg + 32; i++) {
      float dt = px * xyz2s[i * 3] + py * xyz2s[i * 3 + 1] + pz * xyz2s[i * 3 + 2];
      float d = pn + n2s[i] - 2.f * dt;
      if (d < d0) {
        d2v = d1; i2 = i1; d1 = d0; i1 = i0; d0 = d; i0 = i;
      } else if (d < d1) {
        d2v = d1; i2 = i1; d1 = d; i1 = i;
      } else if (d < d2v) {
        d2v = d; i2 = i;
      }
    }
    int base = ql * 13 + qt * 3;
    candd[base] = d0;      candi[base] = i0;
    candd[base + 1] = d1;  candi[base + 1] = i1;
    candd[base + 2] = d2v; candi[base + 2] = i2;
  }
  __syncthreads();

  // ---- phase 1b: merge 12 candidates per query (t<64) ----
  if (t < 64) {
    float d0 = 1e30f, d1 = 1e30f, d2v = 1e30f;
    int i0 = 0, i1 = 0, i2 = 0;
    int base = t * 13;
#pragma unroll
    for (int c = 0; c < 12; c++) {
      float d = candd[base + c];
      int id = candi[base + c];
      if (d < d0) {
        d2v = d1; i2 = i1; d1 = d0; i1 = i0; d0 = d; i0 = id;
      } else if (d < d1) {
        d2v = d1; i2 = i1; d1 = d; i1 = id;
      } else if (d < d2v) {
        d2v = d; i2 = id;
      }
    }
    idxb[t] = i0;
    idxb[64 + t] = i1;
    idxb[128 + t] = i2;
  }
  __syncthreads();

  // ---- phase 1c: pos embed, one (query, neighbor) per thread (t<192) ----
  if (t < 192) {
    const int ql = t & 63;
    const int q = qb + ql;
    const float px = xyz1[q * 3], py = xyz1[q * 3 + 1], pz = xyz1[q * 3 + 2];
    const int id = idxb[t];
    float rx = px - xyz2s[id * 3];
    float ry = py - xyz2s[id * 3 + 1];
    float rz = pz - xyz2s[id * 3 + 2];
    float rn = sqrtf(rx * rx + ry * ry + rz * rz);
    float inv = 1.f / fmaxf(rn, 1e-12f);
    float ux = rx * inv, uy = ry * inv, uz = rz * inv;
    const float* L = lrfs + id * 9;
    float a0 = L[0] * ux + L[1] * uy + L[2] * uz;
    float a1 = L[3] * ux + L[4] * uy + L[5] * uz;
    float a2 = L[6] * ux + L[7] * uy + L[8] * uz;
    u16* pd = posb + (t >> 4) * 512 + (t & 15) * 8;
#pragma unroll
    for (int o = 0; o < DPOS; o++) {
      float v = wps[o * 4] * rn + wps[o * 4 + 1] * a0 + wps[o * 4 + 2] * a1 +
                wps[o * 4 + 3] * a2;
      v = v * pss[o] + pbs[o];
      v = (v >= 0.f) ? v : 0.2f * v;  // LeakyReLU(0.2)
      pd[(o >> 3) * 128 + (o & 7)] = f2bf(v);
    }
  }
  __syncthreads();

  // ---- phase 2: H0 = relu((F[idx] + pos.W0pos^T)*s0 + b0), via hstage ----
  const int wv = t >> 6, lane = t & 63;
  const int quad = lane >> 4, cc = lane & 15;
  const float* Fr[3];
  int rlv[3];
#pragma unroll
  for (int mt = 0; mt < 3; mt++) {
    int rl = wv * 48 + mt * 16 + cc;  // wave's rows: groups 3*wv+mt
    rlv[mt] = rl;
    Fr[mt] = F + ((size_t)(b * N2Q + idxb[rl])) * H0Q;
  }
  bf16x8 afr[3];
#pragma unroll
  for (int mt = 0; mt < 3; mt++)
    afr[mt] = *(const bf16x8*)((const char*)posb + (wv * 3 + mt) * 1024 + (lane << 4));
  const f32x4 zf = {};
  for (int n0s = 0; n0s < H0Q; n0s += 128) {
    bf16x8 bfr[8];
#pragma unroll
    for (int nt = 0; nt < 8; nt++)
      bfr[nt] = *(const bf16x8*)(w0p + (n0s + nt * 16 + cc) * 32 + quad * 8);
    f32x4 acc[3][8];
#pragma unroll
    for (int mt = 0; mt < 3; mt++)
#pragma unroll
      for (int nt = 0; nt < 8; nt++)  // swapped operands: C row=h, col=query
        acc[mt][nt] = __builtin_amdgcn_mfma_f32_16x16x32_bf16(bfr[nt], afr[mt],
                                                              zf, 0, 0, 0);
#pragma unroll
    for (int nt = 0; nt < 8; nt++) {
      int hb = n0s + nt * 16 + quad * 4;
      f32x4 sv = *(const f32x4*)(s0 + hb);
      f32x4 bvv = *(const f32x4*)(b0 + hb);
#pragma unroll
      for (int mt = 0; mt < 3; mt++) {
        f32x4 fv = *(const f32x4*)(Fr[mt] + hb);
        u16x4 o4;
#pragma unroll
        for (int r = 0; r < 4; r++) {
          float h = (fv[r] + acc[mt][nt][r]) * sv[r] + bvv[r];
          h = h > 0.f ? h : 0.f;
          o4[r] = f2bf(h);
        }
        // LDS stage at [row rl][col nt*16+quad*4] (u16, stride 136)
        *(u16x4*)(hstage + rlv[mt] * 136 + nt * 16 + quad * 4) = o4;
      }
    }
    __syncthreads();
    // coalesced write: 192 rows x 16 chunks of 16B; 12 chunks per thread
#pragma unroll
    for (int it = 0; it < 12; it++) {
      int idx = it * 256 + t;
      int rl = idx >> 4, ch = idx & 15;
      u16x8 v = *(const u16x8*)(hstage + rl * 136 + ch * 8);
      int jj = rl >> 6, ql = rl & 63;
      *(u16x8*)(H0 + ((size_t)(jj * NQ) + qb + ql) * H0Q + n0s + ch * 8) = v;
    }
    __syncthreads();
  }
}

// ---------------------------------------------------------------------------
// gemm2: out[b][n][n1] = sum_j relu((H0_j[q][:] . W1[n][:])*s1[n] + b1[n]).
// BM=64 queries x BN=512 H1-cols; K = 3 planes x 8 K-tiles of BK=64.
// 512 threads = 8 waves (1M x 8N), per-wave C = 64x64 (acc 64 + sum 64 VGPR).
// A (H0) streamed once per block; the 2 blocks sharing a q-tile sit on the
// SAME XCD (A L2-reuse); W1 re-read per block but L2-resident per XCD.
// Double-buffered 72KB tiles: per tile: vmcnt(9) -> barrier -> 16 ds_read ->
// lgkmcnt(0) -> barrier -> stage(kt+2, same buf) -> 32 MFMA. Fold at plane
// boundaries. Epilogue: sum frags -> LDS [512 gn][64 q] f32 (stride 68) ->
// 16 coalesced f32x4 row stores per thread.
__global__ __launch_bounds__(512, 2) void gemm2(const u16* __restrict__ A,
                                                const u16* __restrict__ W,
                                                const float* __restrict__ s,
                                                const float* __restrict__ bz,
                                                float* __restrict__ out) {
  __shared__ alignas(16) char smem[147456];  // 2 x 73728 (A 8KB + B 64KB)
  const int id = blockIdx.x;            // 512 blocks
  const int xcd = id & 7, ix = id >> 3; // ix 0..63
  const int qt = xcd * 32 + (ix >> 1);  // q-tile 0..255; pair on same XCD
  const int n0 = (ix & 1) * 512;
  const int q0 = qt * 64;
  const int t = threadIdx.x;
  const int wv = t >> 6, lane = t & 63;
  const int quad = lane >> 4, cc = lane & 15;
  const int lr = lane & 15, lk = (lane >> 4) * 8;

  // staging source bases (elements)
  const size_t aSrc = (size_t)(q0 + (wv & 3) * 16 + lr) * 512 + (wv >> 2) * 32 + lk;
  size_t bSrc[4];
#pragma unroll
  for (int i = 0; i < 4; i++)
    bSrc[i] = (size_t)(n0 + (wv * 4 + i) * 16 + lr) * 512 + lk;
  const int aDst = wv * 1024 + (lane << 4);

  float sv[4], bv[4];
#pragma unroll
  for (int nt = 0; nt < 4; nt++) {
    int gn = n0 + wv * 64 + nt * 16 + cc;
    sv[nt] = s[gn];
    bv[nt] = bz[gn];
  }

  auto stage = [&](int kt, int bi) {
    const int k0 = (kt & 7) << 6;
    const u16* Ap = A + (size_t)(kt >> 3) * ((size_t)NQ * H0Q);
    char* base = smem + bi * 73728;
    load16_lds(Ap + aSrc + k0, base + aDst);
#pragma unroll
    for (int i = 0; i < 4; i++)
#pragma unroll
      for (int kk = 0; kk < 2; kk++)
        load16_lds(W + bSrc[i] + kk * 32 + k0,
                   base + 8192 + (kk * 32 + wv * 4 + i) * 1024 + (lane << 4));
  };

  f32x4 sum[4][4] = {};
  f32x4 acc[4][4] = {};

  auto fold = [&]() {
#pragma unroll
    for (int mt = 0; mt < 4; mt++)
#pragma unroll
      for (int nt = 0; nt < 4; nt++) {
#pragma unroll
        for (int r = 0; r < 4; r++) {
          float h = acc[mt][nt][r] * sv[nt] + bv[nt];
          sum[mt][nt][r] += (h > 0.f ? h : 0.f);
        }
        acc[mt][nt] = f32x4{};
      }
  };

  auto tile = [&](int kt, bool doStage) {
    const int bi = kt & 1;
    const char* base = smem + bi * 73728;
    bf16x8 af[2][4], bf[2][4];
#pragma unroll
    for (int kk = 0; kk < 2; kk++)
#pragma unroll
      for (int mt = 0; mt < 4; mt++)
        af[kk][mt] = *(const bf16x8*)(base + (kk * 4 + mt) * 1024 + (lane << 4));
#pragma unroll
    for (int kk = 0; kk < 2; kk++)
#pragma unroll
      for (int nt = 0; nt < 4; nt++)
        bf[kk][nt] = *(const bf16x8*)(base + 8192 + (kk * 32 + wv * 4 + nt) * 1024 +
                                      (lane << 4));
    asm volatile("s_waitcnt lgkmcnt(0)" ::: "memory");
    __builtin_amdgcn_s_barrier();
    if (doStage) stage(kt + 2, bi);  // same buffer, just fully read
    __builtin_amdgcn_s_setprio(1);
#pragma unroll
    for (int kk = 0; kk < 2; kk++)
#pragma unroll
      for (int mt = 0; mt < 4; mt++)
#pragma unroll
        for (int nt = 0; nt < 4; nt++)
          acc[mt][nt] = __builtin_amdgcn_mfma_f32_16x16x32_bf16(
              af[kk][mt], bf[kk][nt], acc[mt][nt], 0, 0, 0);
    __builtin_amdgcn_s_setprio(0);
  };

  stage(0, 0);
  stage(1, 1);

  for (int kt = 0; kt < 23; kt++) {
    asm volatile("s_waitcnt vmcnt(9)" ::: "memory");  // tile kt landed
    __builtin_amdgcn_s_barrier();
    tile(kt, kt < 22);
    if ((kt & 7) == 7) fold();  // kt 7, 15: plane boundary
  }
  asm volatile("s_waitcnt vmcnt(0)" ::: "memory");
  __builtin_amdgcn_s_barrier();
  tile(23, false);
  fold();

  // ---- epilogue: LDS transpose -> coalesced row stores ----
  float* fs = (float*)smem;  // [512 gn][68] f32 = 139264B
#pragma unroll
  for (int mt = 0; mt < 4; mt++)
#pragma unroll
    for (int nt = 0; nt < 4; nt++)
#pragma unroll
      for (int r = 0; r < 4; r++)
        fs[(wv * 64 + nt * 16 + cc) * 68 + mt * 16 + quad * 4 + r] =
            sum[mt][nt][r];
  __syncthreads();
  const int bb = q0 >> 11, n1b = q0 & 2047;
#pragma unroll
  for (int it = 0; it < 16; it++) {
    int idx = it * 512 + t;
    int row = idx >> 4, ch = idx & 15;
    f32x4 v = *(const f32x4*)(fs + row * 68 + ch * 4);
    *(f32x4*)(out + ((size_t)(bb * H1Q + n0 + row)) * N1Q + n1b + ch * 4) = v;
  }
}

// ---------------------------------------------------------------------------
extern "C" void kernel_launch(void* const* d_in, const int* in_sizes, int n_in,
                              void* d_out, int out_size, void* d_ws,
                              size_t ws_size, hipStream_t stream) {
  const float* xyz1 = (const float*)d_in[0];
  const float* xyz2 = (const float*)d_in[1];
  const float* feat2 = (const float*)d_in[2];
  const float* lrf2 = (const float*)d_in[3];
  const float* w_pos = (const float*)d_in[4];
  const float* pscale = (const float*)d_in[5];
  const float* pbias = (const float*)d_in[6];
  const float* w0 = (const float*)d_in[7];
  const float* s0 = (const float*)d_in[8];
  const float* b0 = (const float*)d_in[9];
  const float* w1 = (const float*)d_in[10];
  const float* s1 = (const float*)d_in[11];
  const float* b1 = (const float*)d_in[12];
  float* out = (float*)d_out;

  char* ws = (char*)d_ws;
  u16* w0f = (u16*)(ws + WS_W0F);
  u16* w0p = (u16*)(ws + WS_W0P);
  u16* w1b = (u16*)(ws + WS_W1);
  u16* f2b = (u16*)(ws + WS_F2B);
  float* F = (float*)(ws + WS_F);
  u16* H0 = (u16*)(ws + WS_H0);

  convert_inputs<<<933888 / 256, 256, 0, stream>>>(w0, w1, feat2, w0f, w0p,
                                                   w1b, f2b);
  fgemm<<<32, 256, 0, stream>>>(f2b, w0f, F);
  build_h0<<<NQ / 64, 256, 0, stream>>>(xyz1, xyz2, lrf2, w_pos, pscale,
                                        pbias, w0p, F, s0, b0, H0);
  gemm2<<<512, 512, 0, stream>>>(H0, w1b, s1, b1, out);
}